// Round 1
// baseline (825.740 us; speedup 1.0000x reference)
//
#include <hip/hip_runtime.h>

#define BB 32
#define HDIM 256
#define WDIM 256
#define HW 65536
#define KTOP 500
#define NBINS 4096
#define CAP 4096

// NMS'd value: keep heat value only if no in-bounds 3x3 neighbor is strictly greater
__device__ __forceinline__ float nms_val(const float* __restrict__ src, int i) {
    float v = src[i];
    int y = i >> 8, x = i & 255;
    bool keep = true;
#pragma unroll
    for (int dy = -1; dy <= 1; ++dy) {
        int ny = y + dy;
        if (ny < 0 || ny >= HDIM) continue;
#pragma unroll
        for (int dx = -1; dx <= 1; ++dx) {
            if (dx == 0 && dy == 0) continue;
            int nx = x + dx;
            if (nx < 0 || nx >= WDIM) continue;
            if (src[(ny << 8) + nx] > v) keep = false;
        }
    }
    return keep ? v : 0.0f;
}

// One block per (source, batch). blockIdx.x < 32 -> pred_hm (with NMS); else gt_hm (raw).
// Writes ws layout: [pred_xs BB*KTOP][pred_ys][gt_xs][gt_ys]
extern "C" __global__ __launch_bounds__(256)
void topk_kernel(const float* __restrict__ pred_hm, const float* __restrict__ gt_hm,
                 float* __restrict__ ws) {
    __shared__ int hist[NBINS];
    __shared__ unsigned long long keys[CAP];
    __shared__ int s_bt, s_cnt;
    const int tid = threadIdx.x;
    const int b = blockIdx.x & 31;
    const bool is_pred = blockIdx.x < BB;
    const float* src = (is_pred ? pred_hm : gt_hm) + (size_t)b * HW;

    for (int i = tid; i < NBINS; i += 256) hist[i] = 0;
    if (tid == 0) s_cnt = 0;
    __syncthreads();

    // Pass 1: histogram of values (uniform in [0,1), so bin = floor(v*NBINS))
    for (int i = tid; i < HW; i += 256) {
        float v = is_pred ? nms_val(src, i) : src[i];
        int bin = (int)(v * (float)NBINS);
        bin = bin < 0 ? 0 : (bin > NBINS - 1 ? NBINS - 1 : bin);
        atomicAdd(&hist[bin], 1);
    }
    __syncthreads();

    // Find bin containing the 500th-largest value (scan from top; ~30-300 iters)
    if (tid == 0) {
        int cum = 0, bt = 0;
        for (int bi = NBINS - 1; bi >= 0; --bi) {
            cum += hist[bi];
            if (cum >= KTOP) { bt = bi; break; }
        }
        s_bt = bt;
    }
    __syncthreads();
    const int bt = s_bt;

    // Pass 2: compact candidates (all elements with bin >= bt) as sortable keys.
    // key = (value_bits << 32) | ~index  -> descending sort = value desc, index asc
    for (int i = tid; i < HW; i += 256) {
        float v = is_pred ? nms_val(src, i) : src[i];
        int bin = (int)(v * (float)NBINS);
        bin = bin < 0 ? 0 : (bin > NBINS - 1 ? NBINS - 1 : bin);
        if (bin >= bt) {
            int pos = atomicAdd(&s_cnt, 1);
            if (pos < CAP) {
                keys[pos] = ((unsigned long long)__float_as_uint(v) << 32)
                          | (unsigned int)(~(unsigned int)i);
            }
        }
    }
    __syncthreads();
    int cnt = s_cnt;
    if (cnt > CAP) cnt = CAP;
    int M = 512;
    while (M < cnt) M <<= 1;
    for (int i = cnt + tid; i < M; i += 256) keys[i] = 0ull;  // pad sorts last
    __syncthreads();

    // Bitonic sort, descending
    for (int kk = 2; kk <= M; kk <<= 1) {
        for (int j = kk >> 1; j > 0; j >>= 1) {
            for (int i = tid; i < M; i += 256) {
                int ixj = i ^ j;
                if (ixj > i) {
                    unsigned long long a = keys[i], c = keys[ixj];
                    bool desc = ((i & kk) == 0);
                    if (desc ? (a < c) : (a > c)) { keys[i] = c; keys[ixj] = a; }
                }
            }
            __syncthreads();
        }
    }

    float* xs_out = ws + (is_pred ? 0 : 2 * BB * KTOP) + b * KTOP;
    float* ys_out = xs_out + BB * KTOP;
    for (int k2 = tid; k2 < KTOP; k2 += 256) {
        unsigned int lin = ~(unsigned int)(keys[k2] & 0xFFFFFFFFull);
        xs_out[k2] = (float)(lin & 255u);
        ys_out[k2] = (float)(lin >> 8);
    }
}

__device__ __forceinline__ float sl1(float p, float t) {
    float d = fabsf(p - t);
    return d < 1.0f ? 0.5f * d * d : d - 0.5f;
}

extern "C" __global__ __launch_bounds__(256)
void loss_kernel(const float* __restrict__ pred_wh, const float* __restrict__ pred_reg,
                 const float* __restrict__ pred_ct,
                 const float* __restrict__ gt_wh, const float* __restrict__ gt_reg,
                 const float* __restrict__ gt_ct, const int* __restrict__ gt_ind,
                 const int* __restrict__ gt_mask,
                 const float* __restrict__ ws, float* __restrict__ acc) {
    const int tid = threadIdx.x;
    const int b = blockIdx.x;
    float num = 0.0f;
    int totc = 0;
    for (int k = tid; k < KTOP; k += 256) {
        const int idx = b * KTOP + k;
        const int rm = gt_mask[idx];
        if (rm) {
            const int ind = gt_ind[idx];
            const float* pw = pred_wh + (size_t)b * 10 * HW + ind;
            float w0 = pw[0 * HW], w1 = pw[1 * HW], w2 = pw[2 * HW], w3 = pw[3 * HW];
            float w4 = pw[4 * HW], w5 = pw[5 * HW], w6 = pw[6 * HW], w7 = pw[7 * HW];
            float w8 = pw[8 * HW], w9 = pw[9 * HW];
            float r0 = pred_reg[(size_t)b * 2 * HW + ind];
            float r1 = pred_reg[(size_t)b * 2 * HW + HW + ind];
            float ct = pred_ct[(size_t)b * HW + ind];
            float xs = ws[idx] + r0;
            float ys = ws[BB * KTOP + idx] + r1;
            bool m = ct > 0.8f;
            float p0 = xs, p1 = ys, p2, p3, p4, p5, p6, p7, p8, p9;
            if (m) {
                p2 = xs + w0; p3 = ys + w1; p4 = xs + w2; p5 = ys + w3;
                p6 = xs + w4; p7 = ys + w5; p8 = xs + w6; p9 = ys + w7;
            } else {
                p2 = xs;              p3 = ys - w9 * 0.5f;
                p4 = xs + w8 * 0.5f;  p5 = ys;
                p6 = xs;              p7 = ys + w9 * 0.5f;
                p8 = xs - w8 * 0.5f;  p9 = ys;
            }
            const float* gw = gt_wh + (size_t)idx * 10;
            float g0 = gw[0], g1 = gw[1], g2 = gw[2], g3 = gw[3], g4 = gw[4];
            float g5 = gw[5], g6 = gw[6], g7 = gw[7], g8 = gw[8], g9 = gw[9];
            float gxs = ws[2 * BB * KTOP + idx] + gt_reg[(size_t)idx * 2 + 0];
            float gys = ws[3 * BB * KTOP + idx] + gt_reg[(size_t)idx * 2 + 1];
            bool gm = gt_ct[idx] > 0.8f;
            float t0 = gxs, t1 = gys, t2, t3, t4, t5, t6, t7, t8, t9;
            if (gm) {
                t2 = gxs + g0; t3 = gys + g1; t4 = gxs + g2; t5 = gys + g3;
                t6 = gxs + g4; t7 = gys + g5; t8 = gxs + g6; t9 = gys + g7;
            } else {
                t2 = gxs;             t3 = gys - g9 * 0.5f;
                t4 = gxs + g8 * 0.5f; t5 = gys;
                t6 = gxs;             t7 = gys + g9 * 0.5f;
                t8 = gxs - g8 * 0.5f; t9 = gys;
            }
            num += sl1(p0, t0) + sl1(p1, t1) + sl1(p2, t2) + sl1(p3, t3) + sl1(p4, t4)
                 + sl1(p5, t5) + sl1(p6, t6) + sl1(p7, t7) + sl1(p8, t8) + sl1(p9, t9);
            totc += 10;
        }
    }
    __shared__ float rn[256];
    __shared__ int rt[256];
    rn[tid] = num;
    rt[tid] = totc;
    __syncthreads();
    for (int s = 128; s > 0; s >>= 1) {
        if (tid < s) { rn[tid] += rn[tid + s]; rt[tid] += rt[tid + s]; }
        __syncthreads();
    }
    if (tid == 0) {
        atomicAdd(&acc[0], rn[0]);
        atomicAdd((int*)(acc + 1), rt[0]);
    }
}

extern "C" __global__ void finalize_kernel(const float* __restrict__ acc, float* __restrict__ out) {
    float num = acc[0];
    float tot = (float)(*(const int*)(acc + 1));
    out[0] = tot > 0.0f ? num / fmaxf(tot, 1.0f) : 0.0f;
}

extern "C" void kernel_launch(void* const* d_in, const int* in_sizes, int n_in,
                              void* d_out, int out_size, void* d_ws, size_t ws_size,
                              hipStream_t stream) {
    const float* pred_hm  = (const float*)d_in[0];
    const float* pred_wh  = (const float*)d_in[1];
    const float* pred_reg = (const float*)d_in[2];
    const float* pred_ct  = (const float*)d_in[3];
    const float* gt_hm    = (const float*)d_in[4];
    const float* gt_wh    = (const float*)d_in[5];
    const float* gt_reg   = (const float*)d_in[6];
    const float* gt_ct    = (const float*)d_in[7];
    const int*   gt_ind   = (const int*)d_in[8];
    const int*   gt_mask  = (const int*)d_in[9];

    float* ws  = (float*)d_ws;
    float* acc = ws + 4 * BB * KTOP;  // 2 floats: [num, tot(int)]

    hipMemsetAsync(acc, 0, 2 * sizeof(float), stream);
    topk_kernel<<<2 * BB, 256, 0, stream>>>(pred_hm, gt_hm, ws);
    loss_kernel<<<BB, 256, 0, stream>>>(pred_wh, pred_reg, pred_ct, gt_wh, gt_reg,
                                        gt_ct, gt_ind, gt_mask, ws, acc);
    finalize_kernel<<<1, 1, 0, stream>>>(acc, (float*)d_out);
}

// Round 2
// 369.368 us; speedup vs baseline: 2.2355x; 2.2355x over previous
//
#include <hip/hip_runtime.h>

#define BB 32
#define HDIM 256
#define WDIM 256
#define HW 65536
#define KTOP 500
#define NBINS 4096
#define CAP 2048
#define SPLIT 16          // blocks per (source,batch) map in hist/compact
#define CHUNK (HW / SPLIT) // 4096 elements per block

// ws layout (in floats):
//   [0 .. 64000)            xs/ys outputs: pred_xs, pred_ys, gt_xs, gt_ys (BB*KTOP each)
//   [64000 .. 64002)        acc: loss numerator (float), count (int)
//   [64002 .. 64008)        pad
//   [64008 .. 326152)       hist: 64 maps x 4096 bins (int)
//   [326152 .. 326216)      cnt: 64 ints
//   [326216 .. 326280)      bt:  64 ints
//   [326280 .. )            keys: 64 maps x CAP x u64  (byte offset 1305120, 8-aligned)
#define OFF_XS   0
#define OFF_ACC  64000
#define OFF_HIST 64008
#define OFF_CNT  326152
#define OFF_BT   326216
#define OFF_KEYS 326280

__device__ __forceinline__ float nms_val(const float* __restrict__ src, int i) {
    float v = src[i];
    int y = i >> 8, x = i & 255;
    bool keep = true;
#pragma unroll
    for (int dy = -1; dy <= 1; ++dy) {
        int ny = y + dy;
        if (ny < 0 || ny >= HDIM) continue;
#pragma unroll
        for (int dx = -1; dx <= 1; ++dx) {
            if (dx == 0 && dy == 0) continue;
            int nx = x + dx;
            if (nx < 0 || nx >= WDIM) continue;
            if (src[(ny << 8) + nx] > v) keep = false;
        }
    }
    return keep ? v : 0.0f;
}

__device__ __forceinline__ int val_bin(float v) {
    int bin = (int)(v * (float)NBINS);
    return bin < 0 ? 0 : (bin > NBINS - 1 ? NBINS - 1 : bin);
}

// grid = 64*SPLIT. map = blockIdx.x / SPLIT (0..31 pred w/ NMS, 32..63 gt raw)
extern "C" __global__ __launch_bounds__(256)
void hist_kernel(const float* __restrict__ pred_hm, const float* __restrict__ gt_hm,
                 int* __restrict__ ws_i) {
    __shared__ int hist[NBINS];
    const int tid = threadIdx.x;
    const int map = blockIdx.x / SPLIT;
    const int chunk = blockIdx.x % SPLIT;
    const int b = map & 31;
    const bool is_pred = map < BB;
    const float* src = (is_pred ? pred_hm : gt_hm) + (size_t)b * HW;

    for (int i = tid; i < NBINS; i += 256) hist[i] = 0;
    __syncthreads();

    const int base = chunk * CHUNK;
    for (int i = base + tid; i < base + CHUNK; i += 256) {
        float v = is_pred ? nms_val(src, i) : src[i];
        atomicAdd(&hist[val_bin(v)], 1);
    }
    __syncthreads();

    int* ghist = ws_i + OFF_HIST + map * NBINS;
    for (int i = tid; i < NBINS; i += 256) {
        int h = hist[i];
        if (h) atomicAdd(&ghist[i], h);
    }
}

// grid = 64 blocks; find threshold bin (500th largest) per map
extern "C" __global__ __launch_bounds__(256)
void thresh_kernel(int* __restrict__ ws_i) {
    __shared__ int segsum[256];
    __shared__ int sbins[NBINS];
    const int tid = threadIdx.x;
    const int* ghist = ws_i + OFF_HIST + blockIdx.x * NBINS;
    for (int i = tid; i < NBINS; i += 256) sbins[i] = ghist[i];
    __syncthreads();
    int s = 0;
    for (int j = 0; j < 16; ++j) s += sbins[tid * 16 + j];
    segsum[tid] = s;
    __syncthreads();
    if (tid == 0) {
        int cum = 0, bt = 0;
        for (int seg = 255; seg >= 0; --seg) {
            if (cum + segsum[seg] >= KTOP) {
                for (int bi = seg * 16 + 15; bi >= seg * 16; --bi) {
                    cum += sbins[bi];
                    if (cum >= KTOP) { bt = bi; break; }
                }
                break;
            }
            cum += segsum[seg];
        }
        ws_i[OFF_BT + blockIdx.x] = bt;
    }
}

// grid = 64*SPLIT; emit candidate keys (value desc, index asc packing)
extern "C" __global__ __launch_bounds__(256)
void compact_kernel(const float* __restrict__ pred_hm, const float* __restrict__ gt_hm,
                    int* __restrict__ ws_i) {
    const int tid = threadIdx.x;
    const int map = blockIdx.x / SPLIT;
    const int chunk = blockIdx.x % SPLIT;
    const int b = map & 31;
    const bool is_pred = map < BB;
    const float* src = (is_pred ? pred_hm : gt_hm) + (size_t)b * HW;
    const int bt = ws_i[OFF_BT + map];
    unsigned long long* keys = (unsigned long long*)(ws_i + OFF_KEYS) + (size_t)map * CAP;
    int* cnt = ws_i + OFF_CNT + map;

    const int base = chunk * CHUNK;
    for (int i = base + tid; i < base + CHUNK; i += 256) {
        float v = is_pred ? nms_val(src, i) : src[i];
        if (val_bin(v) >= bt) {
            int pos = atomicAdd(cnt, 1);
            if (pos < CAP)
                keys[pos] = ((unsigned long long)__float_as_uint(v) << 32)
                          | (unsigned int)(~(unsigned int)i);
        }
    }
}

// grid = 64 blocks; bitonic sort candidates, emit top-500 xs/ys
extern "C" __global__ __launch_bounds__(256)
void sort_kernel(int* __restrict__ ws_i, float* __restrict__ ws_f) {
    __shared__ unsigned long long keys[CAP];
    const int tid = threadIdx.x;
    const int map = blockIdx.x;
    const int b = map & 31;
    const bool is_pred = map < BB;
    const unsigned long long* gkeys = (const unsigned long long*)(ws_i + OFF_KEYS) + (size_t)map * CAP;
    int cnt = ws_i[OFF_CNT + map];
    if (cnt > CAP) cnt = CAP;
    for (int i = tid; i < cnt; i += 256) keys[i] = gkeys[i];
    int M = 512;
    while (M < cnt) M <<= 1;
    for (int i = cnt + tid; i < M; i += 256) keys[i] = 0ull;
    __syncthreads();

    for (int kk = 2; kk <= M; kk <<= 1) {
        for (int j = kk >> 1; j > 0; j >>= 1) {
            for (int i = tid; i < M; i += 256) {
                int ixj = i ^ j;
                if (ixj > i) {
                    unsigned long long a = keys[i], c = keys[ixj];
                    bool desc = ((i & kk) == 0);
                    if (desc ? (a < c) : (a > c)) { keys[i] = c; keys[ixj] = a; }
                }
            }
            __syncthreads();
        }
    }

    float* xs_out = ws_f + OFF_XS + (is_pred ? 0 : 2 * BB * KTOP) + b * KTOP;
    float* ys_out = xs_out + BB * KTOP;
    for (int k2 = tid; k2 < KTOP; k2 += 256) {
        unsigned int lin = ~(unsigned int)(keys[k2] & 0xFFFFFFFFull);
        xs_out[k2] = (float)(lin & 255u);
        ys_out[k2] = (float)(lin >> 8);
    }
}

__device__ __forceinline__ float sl1(float p, float t) {
    float d = fabsf(p - t);
    return d < 1.0f ? 0.5f * d * d : d - 0.5f;
}

// grid = 63 blocks x 256 thr, one (b,k) per thread
extern "C" __global__ __launch_bounds__(256)
void loss_kernel(const float* __restrict__ pred_wh, const float* __restrict__ pred_reg,
                 const float* __restrict__ pred_ct,
                 const float* __restrict__ gt_wh, const float* __restrict__ gt_reg,
                 const float* __restrict__ gt_ct, const int* __restrict__ gt_ind,
                 const int* __restrict__ gt_mask,
                 const float* __restrict__ ws_f, float* __restrict__ acc) {
    const int tid = threadIdx.x;
    const int item = blockIdx.x * 256 + tid;
    float num = 0.0f;
    int totc = 0;
    if (item < BB * KTOP) {
        const int b = item / KTOP;
        const int idx = item;
        if (gt_mask[idx]) {
            const int ind = gt_ind[idx];
            const float* pw = pred_wh + (size_t)b * 10 * HW + ind;
            float w0 = pw[0 * HW], w1 = pw[1 * HW], w2 = pw[2 * HW], w3 = pw[3 * HW];
            float w4 = pw[4 * HW], w5 = pw[5 * HW], w6 = pw[6 * HW], w7 = pw[7 * HW];
            float w8 = pw[8 * HW], w9 = pw[9 * HW];
            float r0 = pred_reg[(size_t)b * 2 * HW + ind];
            float r1 = pred_reg[(size_t)b * 2 * HW + HW + ind];
            float ct = pred_ct[(size_t)b * HW + ind];
            float xs = ws_f[OFF_XS + idx] + r0;
            float ys = ws_f[OFF_XS + BB * KTOP + idx] + r1;
            bool m = ct > 0.8f;
            float p0 = xs, p1 = ys, p2, p3, p4, p5, p6, p7, p8, p9;
            if (m) {
                p2 = xs + w0; p3 = ys + w1; p4 = xs + w2; p5 = ys + w3;
                p6 = xs + w4; p7 = ys + w5; p8 = xs + w6; p9 = ys + w7;
            } else {
                p2 = xs;              p3 = ys - w9 * 0.5f;
                p4 = xs + w8 * 0.5f;  p5 = ys;
                p6 = xs;              p7 = ys + w9 * 0.5f;
                p8 = xs - w8 * 0.5f;  p9 = ys;
            }
            const float* gw = gt_wh + (size_t)idx * 10;
            float g0 = gw[0], g1 = gw[1], g2 = gw[2], g3 = gw[3], g4 = gw[4];
            float g5 = gw[5], g6 = gw[6], g7 = gw[7], g8 = gw[8], g9 = gw[9];
            float gxs = ws_f[OFF_XS + 2 * BB * KTOP + idx] + gt_reg[(size_t)idx * 2 + 0];
            float gys = ws_f[OFF_XS + 3 * BB * KTOP + idx] + gt_reg[(size_t)idx * 2 + 1];
            bool gm = gt_ct[idx] > 0.8f;
            float t0 = gxs, t1 = gys, t2, t3, t4, t5, t6, t7, t8, t9;
            if (gm) {
                t2 = gxs + g0; t3 = gys + g1; t4 = gxs + g2; t5 = gys + g3;
                t6 = gxs + g4; t7 = gys + g5; t8 = gxs + g6; t9 = gys + g7;
            } else {
                t2 = gxs;             t3 = gys - g9 * 0.5f;
                t4 = gxs + g8 * 0.5f; t5 = gys;
                t6 = gxs;             t7 = gys + g9 * 0.5f;
                t8 = gxs - g8 * 0.5f; t9 = gys;
            }
            num = sl1(p0, t0) + sl1(p1, t1) + sl1(p2, t2) + sl1(p3, t3) + sl1(p4, t4)
                + sl1(p5, t5) + sl1(p6, t6) + sl1(p7, t7) + sl1(p8, t8) + sl1(p9, t9);
            totc = 10;
        }
    }
    __shared__ float rn[256];
    __shared__ int rt[256];
    rn[tid] = num;
    rt[tid] = totc;
    __syncthreads();
    for (int s = 128; s > 0; s >>= 1) {
        if (tid < s) { rn[tid] += rn[tid + s]; rt[tid] += rt[tid + s]; }
        __syncthreads();
    }
    if (tid == 0 && rt[0] > 0) {
        atomicAdd(&acc[0], rn[0]);
        atomicAdd((int*)(acc + 1), rt[0]);
    }
}

extern "C" __global__ void finalize_kernel(const float* __restrict__ acc, float* __restrict__ out) {
    float num = acc[0];
    float tot = (float)(*(const int*)(acc + 1));
    out[0] = tot > 0.0f ? num / fmaxf(tot, 1.0f) : 0.0f;
}

extern "C" void kernel_launch(void* const* d_in, const int* in_sizes, int n_in,
                              void* d_out, int out_size, void* d_ws, size_t ws_size,
                              hipStream_t stream) {
    const float* pred_hm  = (const float*)d_in[0];
    const float* pred_wh  = (const float*)d_in[1];
    const float* pred_reg = (const float*)d_in[2];
    const float* pred_ct  = (const float*)d_in[3];
    const float* gt_hm    = (const float*)d_in[4];
    const float* gt_wh    = (const float*)d_in[5];
    const float* gt_reg   = (const float*)d_in[6];
    const float* gt_ct    = (const float*)d_in[7];
    const int*   gt_ind   = (const int*)d_in[8];
    const int*   gt_mask  = (const int*)d_in[9];

    float* ws_f = (float*)d_ws;
    int*   ws_i = (int*)d_ws;
    float* acc  = ws_f + OFF_ACC;

    // zero acc + hist + cnt in one contiguous memset: floats [OFF_ACC, OFF_BT)
    hipMemsetAsync(ws_f + OFF_ACC, 0, (size_t)(OFF_BT - OFF_ACC) * sizeof(float), stream);
    hist_kernel<<<64 * SPLIT, 256, 0, stream>>>(pred_hm, gt_hm, ws_i);
    thresh_kernel<<<64, 256, 0, stream>>>(ws_i);
    compact_kernel<<<64 * SPLIT, 256, 0, stream>>>(pred_hm, gt_hm, ws_i);
    sort_kernel<<<64, 256, 0, stream>>>(ws_i, ws_f);
    loss_kernel<<<63, 256, 0, stream>>>(pred_wh, pred_reg, pred_ct, gt_wh, gt_reg,
                                        gt_ct, gt_ind, gt_mask, ws_f, acc);
    finalize_kernel<<<1, 1, 0, stream>>>(acc, (float*)d_out);
}

// Round 3
// 331.379 us; speedup vs baseline: 2.4918x; 1.1146x over previous
//
#include <hip/hip_runtime.h>

#define BB 32
#define HDIM 256
#define WDIM 256
#define HW 65536
#define KTOP 500
#define NBINS 4096
#define CAP 2048
#define SPLIT 32           // blocks per (source,batch) map in hist/compact
#define CHUNK (HW / SPLIT) // 2048 elements per block

// ws layout (in floats):
//   [0 .. 64000)            xs/ys outputs: pred_xs, pred_ys, gt_xs, gt_ys (BB*KTOP each)
//   [64000 .. 64002)        acc: loss numerator (float), count (int)
//   [64002 .. 64008)        pad
//   [64008 .. 326152)       hist: 64 maps x 4096 bins (int)
//   [326152 .. 326216)      cnt: 64 ints
//   [326216 .. 326280)      bt:  64 ints
//   [326280 .. )            keys: 64 maps x CAP x u64  (byte offset 1305120, 8-aligned)
#define OFF_XS   0
#define OFF_ACC  64000
#define OFF_HIST 64008
#define OFF_CNT  326152
#define OFF_BT   326216
#define OFF_KEYS 326280

// Branchless NMS: replicate-clamp == -inf SAME padding for a windowed max
// (clamped coords always alias an in-window, in-bounds cell). 9 independent
// loads -> single waitcnt, no divergent short-circuit chains.
__device__ __forceinline__ float nms_val(const float* __restrict__ src, int i) {
    const int y = i >> 8, x = i & 255;
    const int ym = (y > 0) ? y - 1 : 0;
    const int yp = (y < HDIM - 1) ? y + 1 : HDIM - 1;
    const int xm = (x > 0) ? x - 1 : 0;
    const int xp = (x < WDIM - 1) ? x + 1 : WDIM - 1;
    const float* r0 = src + (ym << 8);
    const float* r1 = src + (y << 8);
    const float* r2 = src + (yp << 8);
    float a0 = r0[xm], a1 = r0[x], a2 = r0[xp];
    float b0 = r1[xm], b1 = r1[x], b2 = r1[xp];
    float c0 = r2[xm], c1 = r2[x], c2 = r2[xp];
    float h = fmaxf(fmaxf(fmaxf(a0, a1), fmaxf(a2, b0)),
                    fmaxf(fmaxf(b1, b2), fmaxf(fmaxf(c0, c1), c2)));
    return (h <= b1) ? b1 : 0.0f;
}

__device__ __forceinline__ int val_bin(float v) {
    int bin = (int)(v * (float)NBINS);
    return bin < 0 ? 0 : (bin > NBINS - 1 ? NBINS - 1 : bin);
}

// grid = 64*SPLIT. map = blockIdx.x / SPLIT (0..31 pred w/ NMS, 32..63 gt raw)
extern "C" __global__ __launch_bounds__(256)
void hist_kernel(const float* __restrict__ pred_hm, const float* __restrict__ gt_hm,
                 int* __restrict__ ws_i) {
    __shared__ int hist[NBINS];
    const int tid = threadIdx.x;
    const int map = blockIdx.x / SPLIT;
    const int chunk = blockIdx.x % SPLIT;
    const int b = map & 31;
    const bool is_pred = map < BB;
    const float* src = (is_pred ? pred_hm : gt_hm) + (size_t)b * HW;

    for (int i = tid; i < NBINS; i += 256) hist[i] = 0;
    __syncthreads();

    const int base = chunk * CHUNK;
    for (int i = base + tid; i < base + CHUNK; i += 256) {
        float v = is_pred ? nms_val(src, i) : src[i];
        atomicAdd(&hist[val_bin(v)], 1);
    }
    __syncthreads();

    int* ghist = ws_i + OFF_HIST + map * NBINS;
    for (int i = tid; i < NBINS; i += 256) {
        int h = hist[i];
        if (h) atomicAdd(&ghist[i], h);
    }
}

// grid = 64 blocks; find threshold bin (500th largest) per map
extern "C" __global__ __launch_bounds__(256)
void thresh_kernel(int* __restrict__ ws_i) {
    __shared__ int segsum[256];
    __shared__ int sbins[NBINS];
    const int tid = threadIdx.x;
    const int* ghist = ws_i + OFF_HIST + blockIdx.x * NBINS;
    for (int i = tid; i < NBINS; i += 256) sbins[i] = ghist[i];
    __syncthreads();
    int s = 0;
    for (int j = 0; j < 16; ++j) s += sbins[tid * 16 + j];
    segsum[tid] = s;
    __syncthreads();
    if (tid == 0) {
        int cum = 0, bt = 0;
        for (int seg = 255; seg >= 0; --seg) {
            if (cum + segsum[seg] >= KTOP) {
                for (int bi = seg * 16 + 15; bi >= seg * 16; --bi) {
                    cum += sbins[bi];
                    if (cum >= KTOP) { bt = bi; break; }
                }
                break;
            }
            cum += segsum[seg];
        }
        ws_i[OFF_BT + blockIdx.x] = bt;
    }
}

// grid = 64*SPLIT; emit candidate keys (value desc, index asc packing)
extern "C" __global__ __launch_bounds__(256)
void compact_kernel(const float* __restrict__ pred_hm, const float* __restrict__ gt_hm,
                    int* __restrict__ ws_i) {
    const int tid = threadIdx.x;
    const int map = blockIdx.x / SPLIT;
    const int chunk = blockIdx.x % SPLIT;
    const int b = map & 31;
    const bool is_pred = map < BB;
    const float* src = (is_pred ? pred_hm : gt_hm) + (size_t)b * HW;
    const int bt = ws_i[OFF_BT + map];
    unsigned long long* keys = (unsigned long long*)(ws_i + OFF_KEYS) + (size_t)map * CAP;
    int* cnt = ws_i + OFF_CNT + map;

    const int base = chunk * CHUNK;
    for (int i = base + tid; i < base + CHUNK; i += 256) {
        float v = is_pred ? nms_val(src, i) : src[i];
        if (val_bin(v) >= bt) {
            int pos = atomicAdd(cnt, 1);
            if (pos < CAP)
                keys[pos] = ((unsigned long long)__float_as_uint(v) << 32)
                          | (unsigned int)(~(unsigned int)i);
        }
    }
}

// grid = 64 blocks; bitonic sort candidates, emit top-500 xs/ys
extern "C" __global__ __launch_bounds__(256)
void sort_kernel(int* __restrict__ ws_i, float* __restrict__ ws_f) {
    __shared__ unsigned long long keys[CAP];
    const int tid = threadIdx.x;
    const int map = blockIdx.x;
    const int b = map & 31;
    const bool is_pred = map < BB;
    const unsigned long long* gkeys = (const unsigned long long*)(ws_i + OFF_KEYS) + (size_t)map * CAP;
    int cnt = ws_i[OFF_CNT + map];
    if (cnt > CAP) cnt = CAP;
    for (int i = tid; i < cnt; i += 256) keys[i] = gkeys[i];
    int M = 512;
    while (M < cnt) M <<= 1;
    for (int i = cnt + tid; i < M; i += 256) keys[i] = 0ull;
    __syncthreads();

    for (int kk = 2; kk <= M; kk <<= 1) {
        for (int j = kk >> 1; j > 0; j >>= 1) {
            for (int i = tid; i < M; i += 256) {
                int ixj = i ^ j;
                if (ixj > i) {
                    unsigned long long a = keys[i], c = keys[ixj];
                    bool desc = ((i & kk) == 0);
                    if (desc ? (a < c) : (a > c)) { keys[i] = c; keys[ixj] = a; }
                }
            }
            __syncthreads();
        }
    }

    float* xs_out = ws_f + OFF_XS + (is_pred ? 0 : 2 * BB * KTOP) + b * KTOP;
    float* ys_out = xs_out + BB * KTOP;
    for (int k2 = tid; k2 < KTOP; k2 += 256) {
        unsigned int lin = ~(unsigned int)(keys[k2] & 0xFFFFFFFFull);
        xs_out[k2] = (float)(lin & 255u);
        ys_out[k2] = (float)(lin >> 8);
    }
}

__device__ __forceinline__ float sl1(float p, float t) {
    float d = fabsf(p - t);
    return d < 1.0f ? 0.5f * d * d : d - 0.5f;
}

// grid = 63 blocks x 256 thr, one (b,k) per thread
extern "C" __global__ __launch_bounds__(256)
void loss_kernel(const float* __restrict__ pred_wh, const float* __restrict__ pred_reg,
                 const float* __restrict__ pred_ct,
                 const float* __restrict__ gt_wh, const float* __restrict__ gt_reg,
                 const float* __restrict__ gt_ct, const int* __restrict__ gt_ind,
                 const int* __restrict__ gt_mask,
                 const float* __restrict__ ws_f, float* __restrict__ acc) {
    const int tid = threadIdx.x;
    const int item = blockIdx.x * 256 + tid;
    float num = 0.0f;
    int totc = 0;
    if (item < BB * KTOP) {
        const int b = item / KTOP;
        const int idx = item;
        if (gt_mask[idx]) {
            const int ind = gt_ind[idx];
            const float* pw = pred_wh + (size_t)b * 10 * HW + ind;
            float w0 = pw[0 * HW], w1 = pw[1 * HW], w2 = pw[2 * HW], w3 = pw[3 * HW];
            float w4 = pw[4 * HW], w5 = pw[5 * HW], w6 = pw[6 * HW], w7 = pw[7 * HW];
            float w8 = pw[8 * HW], w9 = pw[9 * HW];
            float r0 = pred_reg[(size_t)b * 2 * HW + ind];
            float r1 = pred_reg[(size_t)b * 2 * HW + HW + ind];
            float ct = pred_ct[(size_t)b * HW + ind];
            float xs = ws_f[OFF_XS + idx] + r0;
            float ys = ws_f[OFF_XS + BB * KTOP + idx] + r1;
            bool m = ct > 0.8f;
            float p0 = xs, p1 = ys, p2, p3, p4, p5, p6, p7, p8, p9;
            if (m) {
                p2 = xs + w0; p3 = ys + w1; p4 = xs + w2; p5 = ys + w3;
                p6 = xs + w4; p7 = ys + w5; p8 = xs + w6; p9 = ys + w7;
            } else {
                p2 = xs;              p3 = ys - w9 * 0.5f;
                p4 = xs + w8 * 0.5f;  p5 = ys;
                p6 = xs;              p7 = ys + w9 * 0.5f;
                p8 = xs - w8 * 0.5f;  p9 = ys;
            }
            const float* gw = gt_wh + (size_t)idx * 10;
            float g0 = gw[0], g1 = gw[1], g2 = gw[2], g3 = gw[3], g4 = gw[4];
            float g5 = gw[5], g6 = gw[6], g7 = gw[7], g8 = gw[8], g9 = gw[9];
            float gxs = ws_f[OFF_XS + 2 * BB * KTOP + idx] + gt_reg[(size_t)idx * 2 + 0];
            float gys = ws_f[OFF_XS + 3 * BB * KTOP + idx] + gt_reg[(size_t)idx * 2 + 1];
            bool gm = gt_ct[idx] > 0.8f;
            float t0 = gxs, t1 = gys, t2, t3, t4, t5, t6, t7, t8, t9;
            if (gm) {
                t2 = gxs + g0; t3 = gys + g1; t4 = gxs + g2; t5 = gys + g3;
                t6 = gxs + g4; t7 = gys + g5; t8 = gxs + g6; t9 = gys + g7;
            } else {
                t2 = gxs;             t3 = gys - g9 * 0.5f;
                t4 = gxs + g8 * 0.5f; t5 = gys;
                t6 = gxs;             t7 = gys + g9 * 0.5f;
                t8 = gxs - g8 * 0.5f; t9 = gys;
            }
            num = sl1(p0, t0) + sl1(p1, t1) + sl1(p2, t2) + sl1(p3, t3) + sl1(p4, t4)
                + sl1(p5, t5) + sl1(p6, t6) + sl1(p7, t7) + sl1(p8, t8) + sl1(p9, t9);
            totc = 10;
        }
    }
    __shared__ float rn[256];
    __shared__ int rt[256];
    rn[tid] = num;
    rt[tid] = totc;
    __syncthreads();
    for (int s = 128; s > 0; s >>= 1) {
        if (tid < s) { rn[tid] += rn[tid + s]; rt[tid] += rt[tid + s]; }
        __syncthreads();
    }
    if (tid == 0 && rt[0] > 0) {
        atomicAdd(&acc[0], rn[0]);
        atomicAdd((int*)(acc + 1), rt[0]);
    }
}

extern "C" __global__ void finalize_kernel(const float* __restrict__ acc, float* __restrict__ out) {
    float num = acc[0];
    float tot = (float)(*(const int*)(acc + 1));
    out[0] = tot > 0.0f ? num / fmaxf(tot, 1.0f) : 0.0f;
}

extern "C" void kernel_launch(void* const* d_in, const int* in_sizes, int n_in,
                              void* d_out, int out_size, void* d_ws, size_t ws_size,
                              hipStream_t stream) {
    const float* pred_hm  = (const float*)d_in[0];
    const float* pred_wh  = (const float*)d_in[1];
    const float* pred_reg = (const float*)d_in[2];
    const float* pred_ct  = (const float*)d_in[3];
    const float* gt_hm    = (const float*)d_in[4];
    const float* gt_wh    = (const float*)d_in[5];
    const float* gt_reg   = (const float*)d_in[6];
    const float* gt_ct    = (const float*)d_in[7];
    const int*   gt_ind   = (const int*)d_in[8];
    const int*   gt_mask  = (const int*)d_in[9];

    float* ws_f = (float*)d_ws;
    int*   ws_i = (int*)d_ws;
    float* acc  = ws_f + OFF_ACC;

    // zero acc + hist + cnt in one contiguous memset: floats [OFF_ACC, OFF_BT)
    hipMemsetAsync(ws_f + OFF_ACC, 0, (size_t)(OFF_BT - OFF_ACC) * sizeof(float), stream);
    hist_kernel<<<64 * SPLIT, 256, 0, stream>>>(pred_hm, gt_hm, ws_i);
    thresh_kernel<<<64, 256, 0, stream>>>(ws_i);
    compact_kernel<<<64 * SPLIT, 256, 0, stream>>>(pred_hm, gt_hm, ws_i);
    sort_kernel<<<64, 256, 0, stream>>>(ws_i, ws_f);
    loss_kernel<<<63, 256, 0, stream>>>(pred_wh, pred_reg, pred_ct, gt_wh, gt_reg,
                                        gt_ct, gt_ind, gt_mask, ws_f, acc);
    finalize_kernel<<<1, 1, 0, stream>>>(acc, (float*)d_out);
}